// Round 1
// baseline (323.688 us; speedup 1.0000x reference)
//
#include <hip/hip_runtime.h>

#define EPSC 1e-4f

// ws layout: [0..7] softmax(w), [8..39] m (cumsum thresholds), [40] b
__global__ void setup_kernel(const float* __restrict__ w,
                             const float* __restrict__ r_dist,
                             const float* __restrict__ b,
                             float* __restrict__ ws) {
    if (threadIdx.x == 0 && blockIdx.x == 0) {
        // softmax over H=8 heads (max-subtracted, like jax.nn.softmax)
        float wm = w[0];
        #pragma unroll
        for (int i = 1; i < 8; ++i) wm = fmaxf(wm, w[i]);
        float e[8];
        float s = 0.f;
        #pragma unroll
        for (int i = 0; i < 8; ++i) { e[i] = __expf(w[i] - wm); s += e[i]; }
        float inv = 1.0f / s;
        #pragma unroll
        for (int i = 0; i < 8; ++i) ws[i] = e[i] * inv;
        // m = relu(cumsum(|r_dist + eps| + eps)) over C=32
        float acc = 0.f;
        for (int c = 0; c < 32; ++c) {
            acc += fabsf(r_dist[c] + EPSC) + EPSC;
            ws[8 + c] = fmaxf(acc, 0.f);
        }
        ws[40] = b[0];
    }
}

// 32 lanes cooperate on one edge:
//  - lane l loads float4 slice l of h[src] and h[dst]  (512B coalesced)
//  - 4 lanes per head (D=16): shfl_xor(1,2) reduce -> per-head sum of squares
//  - sqrt * weight[head], shfl_xor(4,8,16) reduce -> dist in all 32 lanes
//  - lane l computes score for cluster c=l, contiguous 128B store
__global__ __launch_bounds__(256) void score_kernel(
    const float* __restrict__ h,
    const int* __restrict__ src,
    const int* __restrict__ dst,
    const float* __restrict__ ws,
    float* __restrict__ out,
    int E) {
    __shared__ float s_w[8];
    __shared__ float s_m[32];
    __shared__ float s_b;
    if (threadIdx.x < 8)  s_w[threadIdx.x] = ws[threadIdx.x];
    if (threadIdx.x < 32) s_m[threadIdx.x] = ws[8 + threadIdx.x];
    if (threadIdx.x == 0) s_b = ws[40];
    __syncthreads();

    const int lane32 = threadIdx.x & 31;   // position within 32-lane group
    const int group  = threadIdx.x >> 5;   // 8 groups per 256-thread block
    const int gid    = blockIdx.x * 8 + group;
    const int stride = gridDim.x * 8;

    const int   head = lane32 >> 2;        // 4 lanes per head
    const float wgt  = s_w[head];
    const float m_c  = s_m[lane32];
    const float bb   = s_b;

    for (int e = gid; e < E; e += stride) {
        const int si = src[e];
        const int di = dst[e];
        const float4* ps = (const float4*)(h + (size_t)si * 128);
        const float4* pd = (const float4*)(h + (size_t)di * 128);
        float4 a = ps[lane32];
        float4 c = pd[lane32];
        float dx = c.x - a.x, dy = c.y - a.y, dz = c.z - a.z, dw = c.w - a.w;
        float ss = dx * dx + dy * dy + dz * dz + dw * dw;
        // reduce within the 4-lane head group
        ss += __shfl_xor(ss, 1);
        ss += __shfl_xor(ss, 2);
        float t = sqrtf(ss) * wgt;
        // reduce across the 8 head groups (bits 2..4 of lane index)
        t += __shfl_xor(t, 4);
        t += __shfl_xor(t, 8);
        t += __shfl_xor(t, 16);
        // t == dist for this edge, identical in all 32 lanes
        float dm = t - m_c;
        out[(size_t)e * 32 + lane32] = 1.0f / (dm * dm + bb);
    }
}

extern "C" void kernel_launch(void* const* d_in, const int* in_sizes, int n_in,
                              void* d_out, int out_size, void* d_ws, size_t ws_size,
                              hipStream_t stream) {
    const float* h      = (const float*)d_in[0];
    const float* w      = (const float*)d_in[1];
    const float* r_dist = (const float*)d_in[2];
    const float* b      = (const float*)d_in[3];
    const int*   src    = (const int*)d_in[4];
    const int*   dst    = (const int*)d_in[5];
    float* out = (float*)d_out;
    float* ws  = (float*)d_ws;
    const int E = in_sizes[4];

    setup_kernel<<<1, 64, 0, stream>>>(w, r_dist, b, ws);
    score_kernel<<<2048, 256, 0, stream>>>(h, src, dst, ws, out, E);
}

// Round 2
// 313.833 us; speedup vs baseline: 1.0314x; 1.0314x over previous
//
#include <hip/hip_runtime.h>

#define EPSC 1e-4f
#define EPB 1024   // edges per block (256 threads = 8 groups of 32 lanes)
#define EPG 128    // edges per 32-lane group

// ws layout: [0..7] softmax(w), [8..39] m (cumsum thresholds), [40] b
__global__ void setup_kernel(const float* __restrict__ w,
                             const float* __restrict__ r_dist,
                             const float* __restrict__ b,
                             float* __restrict__ ws) {
    if (threadIdx.x == 0 && blockIdx.x == 0) {
        float wm = w[0];
        #pragma unroll
        for (int i = 1; i < 8; ++i) wm = fmaxf(wm, w[i]);
        float e[8];
        float s = 0.f;
        #pragma unroll
        for (int i = 0; i < 8; ++i) { e[i] = __expf(w[i] - wm); s += e[i]; }
        float inv = 1.0f / s;
        #pragma unroll
        for (int i = 0; i < 8; ++i) ws[i] = e[i] * inv;
        float acc = 0.f;
        for (int c = 0; c < 32; ++c) {
            acc += fabsf(r_dist[c] + EPSC) + EPSC;
            ws[8 + c] = fmaxf(acc, 0.f);
        }
        ws[40] = b[0];
    }
}

// per-edge score for one lane's cluster; dist reduced across the 32-lane group
__device__ __forceinline__ float edge_dist(float4 a, float4 c, float wgt) {
    float dx = c.x - a.x, dy = c.y - a.y, dz = c.z - a.z, dw = c.w - a.w;
    float ss = dx * dx + dy * dy + dz * dz + dw * dw;
    ss += __shfl_xor(ss, 1);
    ss += __shfl_xor(ss, 2);
    float t = sqrtf(ss) * wgt;
    t += __shfl_xor(t, 4);
    t += __shfl_xor(t, 8);
    t += __shfl_xor(t, 16);
    return t;   // identical across the 32-lane group
}

__global__ __launch_bounds__(256) void score_kernel(
    const float* __restrict__ h,
    const int* __restrict__ src,
    const int* __restrict__ dst,
    const float* __restrict__ ws,
    float* __restrict__ out,
    int E) {
    __shared__ int s_src[EPB];
    __shared__ int s_dst[EPB];
    __shared__ float s_w[8];
    __shared__ float s_m[32];
    __shared__ float s_b;

    const int t = threadIdx.x;
    if (t < 8)  s_w[t] = ws[t];
    if (t < 32) s_m[t] = ws[8 + t];
    if (t == 0) s_b = ws[40];

    const long long base = (long long)blockIdx.x * EPB;

    // stage this block's 1024 src/dst indices into LDS, coalesced
    if (base + EPB <= (long long)E) {
        const int4* ps = (const int4*)(src + base);
        const int4* pd = (const int4*)(dst + base);
        ((int4*)s_src)[t] = ps[t];
        ((int4*)s_dst)[t] = pd[t];
    } else {
        for (int i = t; i < EPB; i += 256) {
            long long e = base + i;
            s_src[i] = (e < (long long)E) ? (int)src[e] : 0;
            s_dst[i] = (e < (long long)E) ? (int)dst[e] : 0;
        }
    }
    __syncthreads();

    const int lane32 = t & 31;
    const int group  = t >> 5;
    const int head   = lane32 >> 2;
    const float wgt  = s_w[head];
    const float m_c  = s_m[lane32];
    const float bb   = s_b;

    const int g0 = group * EPG;   // this group's offset within the block chunk

    for (int j = 0; j < EPG; j += 4) {
        const int i0 = g0 + j;
        const long long e0 = base + i0;
        if (e0 >= (long long)E) break;

        if (e0 + 4 <= (long long)E) {
            // load 4 edges' indices from LDS (broadcast within group)
            const int si0 = s_src[i0 + 0], di0 = s_dst[i0 + 0];
            const int si1 = s_src[i0 + 1], di1 = s_dst[i0 + 1];
            const int si2 = s_src[i0 + 2], di2 = s_dst[i0 + 2];
            const int si3 = s_src[i0 + 3], di3 = s_dst[i0 + 3];
            // issue all 8 gathers back-to-back (4 KB in flight per group)
            float4 a0 = ((const float4*)(h + (size_t)si0 * 128))[lane32];
            float4 c0 = ((const float4*)(h + (size_t)di0 * 128))[lane32];
            float4 a1 = ((const float4*)(h + (size_t)si1 * 128))[lane32];
            float4 c1 = ((const float4*)(h + (size_t)di1 * 128))[lane32];
            float4 a2 = ((const float4*)(h + (size_t)si2 * 128))[lane32];
            float4 c2 = ((const float4*)(h + (size_t)di2 * 128))[lane32];
            float4 a3 = ((const float4*)(h + (size_t)si3 * 128))[lane32];
            float4 c3 = ((const float4*)(h + (size_t)di3 * 128))[lane32];

            float t0 = edge_dist(a0, c0, wgt);
            float t1 = edge_dist(a1, c1, wgt);
            float t2 = edge_dist(a2, c2, wgt);
            float t3 = edge_dist(a3, c3, wgt);

            float d0 = t0 - m_c, d1 = t1 - m_c, d2 = t2 - m_c, d3 = t3 - m_c;
            float v0 = 1.0f / (d0 * d0 + bb);
            float v1 = 1.0f / (d1 * d1 + bb);
            float v2 = 1.0f / (d2 * d2 + bb);
            float v3 = 1.0f / (d3 * d3 + bb);

            float* o = out + (size_t)e0 * 32 + lane32;
            __builtin_nontemporal_store(v0, o);
            __builtin_nontemporal_store(v1, o + 32);
            __builtin_nontemporal_store(v2, o + 64);
            __builtin_nontemporal_store(v3, o + 96);
        } else {
            // tail: scalar-guarded edges
            for (int k = 0; k < 4; ++k) {
                long long e = e0 + k;
                if (e >= (long long)E) break;
                const int si = s_src[i0 + k], di = s_dst[i0 + k];
                float4 a = ((const float4*)(h + (size_t)si * 128))[lane32];
                float4 c = ((const float4*)(h + (size_t)di * 128))[lane32];
                float tt = edge_dist(a, c, wgt);
                float dm = tt - m_c;
                __builtin_nontemporal_store(1.0f / (dm * dm + bb),
                                            out + (size_t)e * 32 + lane32);
            }
        }
    }
}

extern "C" void kernel_launch(void* const* d_in, const int* in_sizes, int n_in,
                              void* d_out, int out_size, void* d_ws, size_t ws_size,
                              hipStream_t stream) {
    const float* h      = (const float*)d_in[0];
    const float* w      = (const float*)d_in[1];
    const float* r_dist = (const float*)d_in[2];
    const float* b      = (const float*)d_in[3];
    const int*   src    = (const int*)d_in[4];
    const int*   dst    = (const int*)d_in[5];
    float* out = (float*)d_out;
    float* ws  = (float*)d_ws;
    const int E = in_sizes[4];

    const int nblocks = (E + EPB - 1) / EPB;
    setup_kernel<<<1, 64, 0, stream>>>(w, r_dist, b, ws);
    score_kernel<<<nblocks, 256, 0, stream>>>(h, src, dst, ws, out, E);
}

// Round 3
// 298.730 us; speedup vs baseline: 1.0835x; 1.0506x over previous
//
#include <hip/hip_runtime.h>
#include <hip/hip_fp16.h>

#define EPSC  1e-4f
#define THETA 0.05f   // refine margin: fp16 dist error <=~1e-3, score err <= 2e-3/THETA^3 ~ 16
#define EPB   1024    // edges per block (256 threads = 8 groups of 32 lanes)
#define EPG   128     // edges per 32-lane group

// ws layout: float[0..7] softmax(w), float[8..39] m, float[40] b, then at byte
// offset 256: h16 (N*128 halves = 25.6 MB)

// convert h -> fp16 (grid-stride); thread (0,0) also computes the params
__global__ void convert_kernel(const float* __restrict__ h,
                               const float* __restrict__ w,
                               const float* __restrict__ r_dist,
                               const float* __restrict__ b,
                               float* __restrict__ ws,
                               __half* __restrict__ h16,
                               long long n) {
    if (blockIdx.x == 0 && threadIdx.x == 0) {
        float wm = w[0];
        #pragma unroll
        for (int i = 1; i < 8; ++i) wm = fmaxf(wm, w[i]);
        float e[8]; float s = 0.f;
        #pragma unroll
        for (int i = 0; i < 8; ++i) { e[i] = __expf(w[i] - wm); s += e[i]; }
        float inv = 1.0f / s;
        #pragma unroll
        for (int i = 0; i < 8; ++i) ws[i] = e[i] * inv;
        float acc = 0.f;
        for (int c = 0; c < 32; ++c) {
            acc += fabsf(r_dist[c] + EPSC) + EPSC;
            ws[8 + c] = fmaxf(acc, 0.f);
        }
        ws[40] = b[0];
    }
    long long i = ((long long)blockIdx.x * blockDim.x + threadIdx.x) * 4;
    const long long stride = (long long)gridDim.x * blockDim.x * 4;
    for (; i + 3 < n; i += stride) {
        float4 v = *(const float4*)(h + i);
        __half2 p0 = __floats2half2_rn(v.x, v.y);
        __half2 p1 = __floats2half2_rn(v.z, v.w);
        uint2 o;
        o.x = *(unsigned int*)&p0;
        o.y = *(unsigned int*)&p1;
        *(uint2*)(h16 + i) = o;
    }
}

__device__ __forceinline__ float edge_dist32(float4 a, float4 c, float wgt) {
    float dx = c.x - a.x, dy = c.y - a.y, dz = c.z - a.z, dw = c.w - a.w;
    float ss = dx * dx + dy * dy + dz * dz + dw * dw;
    ss += __shfl_xor(ss, 1);
    ss += __shfl_xor(ss, 2);
    float t = sqrtf(ss) * wgt;
    t += __shfl_xor(t, 4);
    t += __shfl_xor(t, 8);
    t += __shfl_xor(t, 16);
    return t;
}

__global__ __launch_bounds__(256) void score_kernel(
    const float* __restrict__ h,
    const __half* __restrict__ h16,
    const int* __restrict__ src,
    const int* __restrict__ dst,
    const float* __restrict__ ws,
    float* __restrict__ out,
    int E) {
    __shared__ int s_src[EPB];
    __shared__ int s_dst[EPB];
    __shared__ float s_w[8];
    __shared__ float s_m[32];
    __shared__ float s_b;

    const int t = threadIdx.x;
    if (t < 8)  s_w[t] = ws[t];
    if (t < 32) s_m[t] = ws[8 + t];
    if (t == 0) s_b = ws[40];

    const long long base = (long long)blockIdx.x * EPB;

    if (base + EPB <= (long long)E) {
        ((int4*)s_src)[t] = ((const int4*)(src + base))[t];
        ((int4*)s_dst)[t] = ((const int4*)(dst + base))[t];
    } else {
        for (int i = t; i < EPB; i += 256) {
            long long e = base + i;
            s_src[i] = (e < (long long)E) ? src[e] : 0;
            s_dst[i] = (e < (long long)E) ? dst[e] : 0;
        }
    }
    __syncthreads();

    const int lane32 = t & 31;
    const int half   = (t >> 5) & 1;     // which half of the wave
    const int group  = t >> 5;
    const int head   = lane32 >> 2;
    const float wgt  = s_w[head];
    const float m_c  = s_m[lane32];
    const float bb   = s_b;

    const int g0 = group * EPG;

    for (int j = 0; j < EPG; j += 4) {
        const int i0 = g0 + j;
        const long long e0 = base + i0;
        if (e0 >= (long long)E) break;

        if (e0 + 4 <= (long long)E) {
            int si[4], di[4];
            uint2 ua[4], uc[4];
            #pragma unroll
            for (int k = 0; k < 4; ++k) {
                si[k] = s_src[i0 + k];
                di[k] = s_dst[i0 + k];
            }
            #pragma unroll
            for (int k = 0; k < 4; ++k) {
                ua[k] = ((const uint2*)(h16 + (size_t)si[k] * 128))[lane32];
                uc[k] = ((const uint2*)(h16 + (size_t)di[k] * 128))[lane32];
            }
            float d[4];
            #pragma unroll
            for (int k = 0; k < 4; ++k) {
                float2 a0 = __half22float2(*(__half2*)&ua[k].x);
                float2 a1 = __half22float2(*(__half2*)&ua[k].y);
                float2 c0 = __half22float2(*(__half2*)&uc[k].x);
                float2 c1 = __half22float2(*(__half2*)&uc[k].y);
                float dx = c0.x - a0.x, dy = c0.y - a0.y;
                float dz = c1.x - a1.x, dw = c1.y - a1.y;
                float ss = dx * dx + dy * dy + dz * dz + dw * dw;
                ss += __shfl_xor(ss, 1);
                ss += __shfl_xor(ss, 2);
                float tt = sqrtf(ss) * wgt;
                tt += __shfl_xor(tt, 4);
                tt += __shfl_xor(tt, 8);
                tt += __shfl_xor(tt, 16);
                d[k] = tt;
            }
            float* o = out + (size_t)e0 * 32 + lane32;
            #pragma unroll
            for (int k = 0; k < 4; ++k) {
                bool near = fabsf(d[k] - m_c) < THETA;
                unsigned long long mask = __ballot(near);
                unsigned int gm = (unsigned int)(mask >> (half ? 32 : 0));
                if (gm) {
                    // refine with exact f32 gather (rare: ~25% of edges)
                    float4 a = ((const float4*)(h + (size_t)si[k] * 128))[lane32];
                    float4 c = ((const float4*)(h + (size_t)di[k] * 128))[lane32];
                    d[k] = edge_dist32(a, c, wgt);
                }
                float dm = d[k] - m_c;
                __builtin_nontemporal_store(1.0f / (dm * dm + bb), o + k * 32);
            }
        } else {
            // tail: exact f32 per edge
            for (int k = 0; k < 4; ++k) {
                long long e = e0 + k;
                if (e >= (long long)E) break;
                const int si = s_src[i0 + k], di = s_dst[i0 + k];
                float4 a = ((const float4*)(h + (size_t)si * 128))[lane32];
                float4 c = ((const float4*)(h + (size_t)di * 128))[lane32];
                float tt = edge_dist32(a, c, wgt);
                float dm = tt - m_c;
                __builtin_nontemporal_store(1.0f / (dm * dm + bb),
                                            out + (size_t)e * 32 + lane32);
            }
        }
    }
}

// fallback: pure-f32 kernel (used if ws is too small for h16)
__global__ __launch_bounds__(256) void score_kernel_f32(
    const float* __restrict__ h,
    const int* __restrict__ src,
    const int* __restrict__ dst,
    const float* __restrict__ ws,
    float* __restrict__ out,
    int E) {
    __shared__ int s_src[EPB];
    __shared__ int s_dst[EPB];
    __shared__ float s_w[8];
    __shared__ float s_m[32];
    __shared__ float s_b;
    const int t = threadIdx.x;
    if (t < 8)  s_w[t] = ws[t];
    if (t < 32) s_m[t] = ws[8 + t];
    if (t == 0) s_b = ws[40];
    const long long base = (long long)blockIdx.x * EPB;
    if (base + EPB <= (long long)E) {
        ((int4*)s_src)[t] = ((const int4*)(src + base))[t];
        ((int4*)s_dst)[t] = ((const int4*)(dst + base))[t];
    } else {
        for (int i = t; i < EPB; i += 256) {
            long long e = base + i;
            s_src[i] = (e < (long long)E) ? src[e] : 0;
            s_dst[i] = (e < (long long)E) ? dst[e] : 0;
        }
    }
    __syncthreads();
    const int lane32 = t & 31;
    const int group  = t >> 5;
    const float wgt  = s_w[lane32 >> 2];
    const float m_c  = s_m[lane32];
    const float bb   = s_b;
    const int g0 = group * EPG;
    for (int j = 0; j < EPG; ++j) {
        const long long e = base + g0 + j;
        if (e >= (long long)E) break;
        const int si = s_src[g0 + j], di = s_dst[g0 + j];
        float4 a = ((const float4*)(h + (size_t)si * 128))[lane32];
        float4 c = ((const float4*)(h + (size_t)di * 128))[lane32];
        float tt = edge_dist32(a, c, wgt);
        float dm = tt - m_c;
        __builtin_nontemporal_store(1.0f / (dm * dm + bb),
                                    out + (size_t)e * 32 + lane32);
    }
}

extern "C" void kernel_launch(void* const* d_in, const int* in_sizes, int n_in,
                              void* d_out, int out_size, void* d_ws, size_t ws_size,
                              hipStream_t stream) {
    const float* h      = (const float*)d_in[0];
    const float* w      = (const float*)d_in[1];
    const float* r_dist = (const float*)d_in[2];
    const float* b      = (const float*)d_in[3];
    const int*   src    = (const int*)d_in[4];
    const int*   dst    = (const int*)d_in[5];
    float* out = (float*)d_out;
    float* ws  = (float*)d_ws;
    const int E = in_sizes[4];
    const long long n_h = (long long)in_sizes[0];   // N*H*D

    const int nblocks = (E + EPB - 1) / EPB;
    const size_t need = 256 + (size_t)n_h * sizeof(__half);

    if (ws_size >= need) {
        __half* h16 = (__half*)((char*)d_ws + 256);
        convert_kernel<<<2048, 256, 0, stream>>>(h, w, r_dist, b, ws, h16, n_h);
        score_kernel<<<nblocks, 256, 0, stream>>>(h, h16, src, dst, ws, out, E);
    } else {
        convert_kernel<<<1, 64, 0, stream>>>(h, w, r_dist, b, ws, (__half*)nullptr, 0);
        score_kernel_f32<<<nblocks, 256, 0, stream>>>(h, src, dst, ws, out, E);
    }
}